// Round 11
// baseline (272.256 us; speedup 1.0000x reference)
//
#include <hip/hip_runtime.h>
#include <stdint.h>

#define B_ 64
#define T_ 2048
#define D_ 256
#define U_ 256
#define BT 256            // T rows per score_ctx block
#define NT (BT / 16)      // 16 tiles of 16 rows
#define NP (NT / 2)       // 8 pair-iterations (32 rows per barrier round-trip)
#define TC (T_ / BT)      // 8 chunks per batch
#define SHIFT_ 8.0f       // fixed softmax shift; |score| <= sum|V_w| ~ 10 -> exp(s-8) fp32-safe

typedef _Float16 half8   __attribute__((ext_vector_type(8)));
typedef __fp16   fp16x2  __attribute__((ext_vector_type(2)));   // cvt_pkrtz native return type
typedef float    floatx4 __attribute__((ext_vector_type(4)));

typedef const __attribute__((address_space(1))) void cg_void;   // global src for DMA
typedef __attribute__((address_space(3))) void       ls_void;   // LDS dst for DMA

// ---------------- Kernel 1 (merged): qproj (blocks 0..63) + w2t (blocks 64..127) ----------
__global__ void prep_kernel(const float* __restrict__ query,
                            const float* __restrict__ W1_w,
                            const float* __restrict__ W1_b,
                            const float* __restrict__ W2_b,
                            const float* __restrict__ W2_w,
                            float* __restrict__ qb,
                            _Float16* __restrict__ w2t) {
    __shared__ float qrow[D_];
    __shared__ float tile[32][33];
    if (blockIdx.x < 64) {
        const int b = blockIdx.x;
        const int u = threadIdx.x;           // 256 == U_
        qrow[u] = query[b * D_ + u];
        __syncthreads();
        float a0 = 0.f, a1 = 0.f, a2 = 0.f, a3 = 0.f;
#pragma unroll 4
        for (int d = 0; d < D_; d += 4) {
            a0 += qrow[d    ] * W1_w[(d    ) * U_ + u];
            a1 += qrow[d + 1] * W1_w[(d + 1) * U_ + u];
            a2 += qrow[d + 2] * W1_w[(d + 2) * U_ + u];
            a3 += qrow[d + 3] * W1_w[(d + 3) * U_ + u];
        }
        qb[b * U_ + u] = (a0 + a1) + (a2 + a3) + W1_b[u] + W2_b[u];
    } else {
        const int bid = blockIdx.x - 64;
        const int tu = bid & 7;              // u tile
        const int td = bid >> 3;             // d tile
        const int c  = threadIdx.x & 31;
        const int r0 = threadIdx.x >> 5;     // 0..7
#pragma unroll
        for (int i = 0; i < 4; ++i) {
            int r = r0 + i * 8;
            tile[r][c] = W2_w[(td * 32 + r) * U_ + tu * 32 + c];
        }
        __syncthreads();
#pragma unroll
        for (int i = 0; i < 4; ++i) {
            int r = r0 + i * 8;              // u within tile
            w2t[(tu * 32 + r) * D_ + td * 32 + c] = (_Float16)tile[c][r];
        }
    }
}

// ---------------- Kernel 2 (fused): scores + fixed-shift partial softmax context ----------------
// R6/R10 post-mortem: counters invariant at ~3000 cyc/tile-slot, MfmaUtil 8%, VALUBusy 38%
// -> ~50% of time is the 2-barriers-per-16-rows round-trip + serial latency chains (bpermute
// reduce, exp), which TLP can't hide (waves barrier-locked). Lever: amortize the fixed
// per-iteration stall over 2x work. PAIR-TILES: 32 rows per barrier round-trip, two
// independent MFMA/epilogue chains (acc0/acc1) for ILP inside each phase. R7's compile bug
// fixed (fp16x2 typedef = cvt_pkrtz return type); R8's hand-asm loads dropped (plain loads
// are resident per R10's pin null-result). Everything else byte-for-byte R6: verified MFMA
// A addressing, XOR swizzle, context mapping, DMA staging, lgkm-only B2.
__launch_bounds__(256, 2)
__global__ void score_ctx_kernel(const float* __restrict__ values,
                                 const _Float16* __restrict__ w2t,
                                 const float* __restrict__ qb,
                                 const float* __restrict__ V_w,
                                 float* __restrict__ scores,
                                 float* __restrict__ pctx,
                                 float* __restrict__ pl) {
    __shared__ __align__(16) float buf[4][16 * D_];    // 4 x 16KB fp32 tile slots
    __shared__ __align__(16) float s_part2[2][16][4];  // [tile of pair][row][wave]
    __shared__ float sbuf[BT];                          // raw scores for this chunk

    const int b     = blockIdx.y;
    const int chunk = blockIdx.x;
    const int tid   = threadIdx.x;
    const int wave  = tid >> 6;
    const int lane  = tid & 63;
    const int n16   = lane & 15;
    const int quad  = lane >> 4;
    const int u0    = wave * 64;

    // --- W2 B-fragments, register-stationary (verified layout; resident per R10) ---
    half8 bfrag[4][8];
#pragma unroll
    for (int ut = 0; ut < 4; ++ut) {
        const int u = u0 + ut * 16 + n16;
#pragma unroll
        for (int k = 0; k < 8; ++k)
            bfrag[ut][k] = *(const half8*)(w2t + u * D_ + k * 32 + quad * 8);
    }

    float qbv[4], vwv[4];
#pragma unroll
    for (int ut = 0; ut < 4; ++ut) {
        const int u = u0 + ut * 16 + n16;
        qbv[ut] = qb[b * U_ + u];
        vwv[ut] = V_w[u];
    }

    const float* vbase = values + (size_t)b * T_ * D_ + (size_t)chunk * BT * D_;

    // MFMA A-operand (verified): global chunk c0=k*8+quad*2 lives at LDS chunk
    // k*8 + ((quad*2)^swz), swz=n16&7. Hoisted bases; k strides 8 chunks = 32 floats.
    const int e0 = (quad * 2) ^ (n16 & 7);
    const int e1 = e0 ^ 1;

    // Context mapping (verified): d=tid -> global chunk g=tid>>2 at LDS chunk g^(row&7).
    const int g = tid >> 2, lo = tid & 3;
    int co[8];
#pragma unroll
    for (int s = 0; s < 8; ++s) co[s] = (((g ^ s) & 63) << 2) + lo;

    float c0a = 0.f, c1a = 0.f;   // context accumulators (two chains), thread owns d=tid
    float l0a = 0.f, l1a = 0.f;   // sum of exp(s - SHIFT_)

    // stage one 16-row tile into slot bi: 16 wave-level DMA ops, 4 per wave
    auto stage = [&](int tile, int bi) {
        const float* src = vbase + tile * 16 * D_;
#pragma unroll
        for (int i = 0; i < 4; ++i) {
            const int r = i * 4 + wave;                          // wave-uniform row
            const float* gp = src + r * D_ + ((lane ^ (r & 7)) << 2);
            float* lp = &buf[bi][r * D_];
            __builtin_amdgcn_global_load_lds((cg_void*)gp, (ls_void*)lp, 16, 0, 0);
        }
    };

    stage(0, 0);
    stage(1, 1);

#pragma unroll 1
    for (int i = 0; i < NP; ++i) {
        const int s0 = (i & 1) << 1;       // this pair's slots: s0, s0+1
        // B1: pair i staged (its DMA had a full iteration of compute in flight behind it).
        asm volatile("s_waitcnt vmcnt(0) lgkmcnt(0)" ::: "memory");
        __builtin_amdgcn_s_barrier();
        asm volatile("" ::: "memory");

        // prefetch pair i+1 into the other slot pair (its last readers passed B1 above);
        // these 8 loads stay in flight through this whole pair's compute.
        if (i + 1 < NP) { stage(2 * i + 2, s0 ^ 2); stage(2 * i + 3, (s0 ^ 2) + 1); }

        // --- phase 1: MFMA for both tiles of the pair (64 MFMA, 2 indep chains) ---
        const float* base0 = &buf[s0][n16 * D_];
        const float* base1 = &buf[s0 + 1][n16 * D_];
        floatx4 acc0[4] = {};
        floatx4 acc1[4] = {};
#pragma unroll
        for (int k = 0; k < 8; ++k) {
            floatx4 q00 = *(const floatx4*)(base0 + (e0 << 2) + (k << 5));
            floatx4 q01 = *(const floatx4*)(base0 + (e1 << 2) + (k << 5));
            floatx4 q10 = *(const floatx4*)(base1 + (e0 << 2) + (k << 5));
            floatx4 q11 = *(const floatx4*)(base1 + (e1 << 2) + (k << 5));
            union { fp16x2 h2[4]; half8 h8; } ua, ub;
            ua.h2[0] = __builtin_amdgcn_cvt_pkrtz(q00.x, q00.y);
            ua.h2[1] = __builtin_amdgcn_cvt_pkrtz(q00.z, q00.w);
            ua.h2[2] = __builtin_amdgcn_cvt_pkrtz(q01.x, q01.y);
            ua.h2[3] = __builtin_amdgcn_cvt_pkrtz(q01.z, q01.w);
            ub.h2[0] = __builtin_amdgcn_cvt_pkrtz(q10.x, q10.y);
            ub.h2[1] = __builtin_amdgcn_cvt_pkrtz(q10.z, q10.w);
            ub.h2[2] = __builtin_amdgcn_cvt_pkrtz(q11.x, q11.y);
            ub.h2[3] = __builtin_amdgcn_cvt_pkrtz(q11.z, q11.w);
#pragma unroll
            for (int ut = 0; ut < 4; ++ut) {
                acc0[ut] = __builtin_amdgcn_mfma_f32_16x16x32_f16(ua.h8, bfrag[ut][k], acc0[ut], 0, 0, 0);
                acc1[ut] = __builtin_amdgcn_mfma_f32_16x16x32_f16(ub.h8, bfrag[ut][k], acc1[ut], 0, 0, 0);
            }
        }

        // --- epilogue: tanh + dot with V_w for both tiles, reduce over u (n16) ---
        float part0[4], part1[4];
#pragma unroll
        for (int r = 0; r < 4; ++r) {
            float sa = 0.f, sb = 0.f;
#pragma unroll
            for (int ut = 0; ut < 4; ++ut) {
                float x0 = acc0[ut][r] + qbv[ut];
                float x1 = acc1[ut][r] + qbv[ut];
                float e0v = __expf(2.f * x0);
                float e1v = __expf(2.f * x1);
                sa += (1.f - __fdividef(2.f, e0v + 1.f)) * vwv[ut];
                sb += (1.f - __fdividef(2.f, e1v + 1.f)) * vwv[ut];
            }
            part0[r] = sa; part1[r] = sb;
        }
#pragma unroll
        for (int m = 1; m < 16; m <<= 1)
#pragma unroll
            for (int r = 0; r < 4; ++r) {
                part0[r] += __shfl_xor(part0[r], m, 16);
                part1[r] += __shfl_xor(part1[r], m, 16);
            }
        if (n16 == 0) {
#pragma unroll
            for (int r = 0; r < 4; ++r) {
                s_part2[0][quad * 4 + r][wave] = part0[r];
                s_part2[1][quad * 4 + r][wave] = part1[r];
            }
        }

        // B2: s_part2 visible (lgkm-only; pair i+1 DMA stays in flight)
        asm volatile("s_waitcnt lgkmcnt(0)" ::: "memory");
        __builtin_amdgcn_s_barrier();
        asm volatile("" ::: "memory");

        // --- phase 2: 32 rows of weights + context FMA (slots s0, s0+1) ---
        const float* sp2 = &s_part2[0][0][0];
        const float* v0  = &buf[s0][0];
#pragma unroll
        for (int t = 0; t < 16; ++t) {
            floatx4 spA = *(const floatx4*)(sp2 + t * 4);            // tile 0 row t
            floatx4 spB = *(const floatx4*)(sp2 + 64 + t * 4);       // tile 1 row t
            float svA = (spA.x + spA.y) + (spA.z + spA.w);
            float svB = (spB.x + spB.y) + (spB.z + spB.w);
            float wA = __expf(svA - SHIFT_);
            float wB = __expf(svB - SHIFT_);
            l0a += wA; l1a += wB;
            c0a += wA * v0[t * D_ + co[t & 7]];
            c1a += wB * v0[16 * D_ + t * D_ + co[t & 7]];
        }
        if (tid < 32) {
            const int p = tid >> 4, r = tid & 15;
            floatx4 sp = *(const floatx4*)(sp2 + p * 64 + r * 4);
            sbuf[i * 32 + tid] = (sp.x + sp.y) + (sp.z + sp.w);
        }
    }

    __syncthreads();   // sbuf visible
    pctx[(b * TC + chunk) * D_ + tid] = c0a + c1a;
    scores[b * T_ + chunk * BT + tid] = sbuf[tid];
    if (tid == 0) pl[b * TC + chunk] = l0a + l1a;
}

// ---------------- Kernel 3: combine partials -> ctx, attn ----------------
__global__ void finalize_kernel(const float* __restrict__ pctx,
                                const float* __restrict__ pl,
                                const float* __restrict__ scores,
                                float* __restrict__ ctx,
                                float* __restrict__ attn) {
    const int b = blockIdx.x, tid = threadIdx.x;   // 256 threads
    float L = 0.f;
#pragma unroll
    for (int i = 0; i < TC; ++i) L += pl[b * TC + i];
    float s = 0.f;
#pragma unroll
    for (int i = 0; i < TC; ++i) s += pctx[(b * TC + i) * D_ + tid];
    const float invL = __fdividef(1.f, L);
    ctx[b * D_ + tid] = s * invL;
#pragma unroll
    for (int j = 0; j < T_ / 256; ++j) {
        const int t = j * 256 + tid;
        attn[b * T_ + t] = __expf(scores[b * T_ + t] - SHIFT_) * invL;
    }
}

extern "C" void kernel_launch(void* const* d_in, const int* in_sizes, int n_in,
                              void* d_out, int out_size, void* d_ws, size_t ws_size,
                              hipStream_t stream) {
    const float* query  = (const float*)d_in[0];
    const float* values = (const float*)d_in[1];
    const float* W1_w   = (const float*)d_in[2];
    const float* W1_b   = (const float*)d_in[3];
    const float* W2_w   = (const float*)d_in[4];
    const float* W2_b   = (const float*)d_in[5];
    const float* V_w    = (const float*)d_in[6];
    // d_in[7] = V_b: softmax is shift-invariant -> no effect on either output.

    float* out  = (float*)d_out;
    float* ctx  = out;                  // [B, D]
    float* attn = out + B_ * D_;        // [B, T]

    char* ws = (char*)d_ws;
    float*    qb     = (float*)ws;                               // B*U fp32       (64 KB)
    _Float16* w2t    = (_Float16*)(ws + (64 << 10));             // U*D fp16       (128 KB)
    float*    scores = (float*)(ws + (192 << 10));               // B*T fp32       (512 KB)
    float*    pctx   = (float*)(ws + (704 << 10));               // B*TC*D fp32    (512 KB)
    float*    pl     = (float*)(ws + (1216 << 10));              // B*TC fp32      (2 KB)

    prep_kernel     <<<dim3(128),     dim3(256), 0, stream>>>(query, W1_w, W1_b, W2_b, W2_w, qb, w2t);
    score_ctx_kernel<<<dim3(TC, B_),  dim3(256), 0, stream>>>(values, w2t, qb, V_w, scores, pctx, pl);
    finalize_kernel <<<dim3(B_),      dim3(256), 0, stream>>>(pctx, pl, scores, ctx, attn);
}